// Round 1
// 209.719 us; speedup vs baseline: 1.0627x; 1.0627x over previous
//
#include <hip/hip_runtime.h>
#include <hip/hip_bf16.h>

typedef __bf16 bf16_t;
typedef bf16_t bf16x8 __attribute__((ext_vector_type(8)));
typedef float f32x4 __attribute__((ext_vector_type(4)));
typedef float f32x16 __attribute__((ext_vector_type(16)));

#define EMB 1024
#define HEADS 16
#define BATCH 2
#define SEQ 2048
#define HD 64
#define TOKENS (BATCH * SEQ)  // 4096

// async global->LDS, 16B per lane. LDS dest = wave-uniform base + lane*16.
__device__ __forceinline__ void gld16(bf16_t* lds_dst, const bf16_t* g_src) {
    __builtin_amdgcn_global_load_lds(
        (const __attribute__((address_space(1))) unsigned int*)g_src,
        (__attribute__((address_space(3))) unsigned int*)lds_dst, 16, 0, 0);
}

__device__ __forceinline__ unsigned cvt_pk_bf16(float lo, float hi) {
    unsigned r;
    asm("v_cvt_pk_bf16_f32 %0, %1, %2" : "=v"(r) : "v"(lo), "v"(hi));
    return r;
}

// ---------------------------------------------------------------------------
// x fp32 -> bf16 (elementwise). 1024 blocks x 256 thr x 16 elems = 4M.
// ---------------------------------------------------------------------------
__global__ __launch_bounds__(256) void convert_x(const float* __restrict__ x,
                                                 bf16_t* __restrict__ xb) {
    size_t i = ((size_t)blockIdx.x * 256 + threadIdx.x) * 16;
    f32x4 v0 = *(const f32x4*)&x[i];
    f32x4 v1 = *(const f32x4*)&x[i + 4];
    f32x4 v2 = *(const f32x4*)&x[i + 8];
    f32x4 v3 = *(const f32x4*)&x[i + 12];
    bf16x8 o0, o1;
#pragma unroll
    for (int j = 0; j < 4; ++j) {
        o0[j] = (bf16_t)v0[j]; o0[4 + j] = (bf16_t)v1[j];
        o1[j] = (bf16_t)v2[j]; o1[4 + j] = (bf16_t)v3[j];
    }
    *(bf16x8*)&xb[i] = o0;
    *(bf16x8*)&xb[i + 8] = o1;
}

// ---------------------------------------------------------------------------
// W[k][n] fp32 -> Wt[n][k] bf16, 64x64 tiles. grid (16,16,4), z picks matrix.
// ---------------------------------------------------------------------------
__global__ __launch_bounds__(256) void prep_w(
    const float* __restrict__ W0, const float* __restrict__ W1,
    const float* __restrict__ W2, const float* __restrict__ W3,
    bf16_t* __restrict__ T0, bf16_t* __restrict__ T1,
    bf16_t* __restrict__ T2, bf16_t* __restrict__ T3) {
    __shared__ __align__(16) bf16_t T[64][72];
    int z = blockIdx.z;
    const float* src = (z == 0) ? W0 : (z == 1) ? W1 : (z == 2) ? W2 : W3;
    bf16_t* dst = (z == 0) ? T0 : (z == 1) ? T1 : (z == 2) ? T2 : T3;
    int k0 = blockIdx.y * 64, n0 = blockIdx.x * 64;
    int r = threadIdx.x >> 2, c4 = (threadIdx.x & 3) * 16;
    f32x4 v[4];
#pragma unroll
    for (int q = 0; q < 4; ++q)
        v[q] = *(const f32x4*)&src[(size_t)(k0 + r) * 1024 + n0 + c4 + q * 4];
#pragma unroll
    for (int j = 0; j < 16; ++j) T[c4 + j][r] = (bf16_t)v[j >> 2][j & 3];
    __syncthreads();
    bf16x8 o0 = *(const bf16x8*)&T[r][c4];
    bf16x8 o1 = *(const bf16x8*)&T[r][c4 + 8];
    *(bf16x8*)&dst[(size_t)(n0 + r) * 1024 + k0 + c4] = o0;
    *(bf16x8*)&dst[(size_t)(n0 + r) * 1024 + k0 + c4 + 8] = o1;
}

// ---------------------------------------------------------------------------
// m97-style GEMM: C[4096][1024] = A @ Wt^T + bias.  BM=128 BN=128 BK=32.
// ---------------------------------------------------------------------------
template <typename TO>
__global__ __launch_bounds__(256) void gemm128(
    const bf16_t* __restrict__ A,
    const bf16_t* __restrict__ Wt0, const bf16_t* __restrict__ Wt1, const bf16_t* __restrict__ Wt2,
    const float* __restrict__ b0, const float* __restrict__ b1, const float* __restrict__ b2,
    TO* __restrict__ o0, TO* __restrict__ o1, TO* __restrict__ o2,
    int md0, int md1, int md2, float sc0, float sc1, float sc2) {
    __shared__ __align__(16) bf16_t As[128 * 32];  // 8 KB
    __shared__ __align__(16) bf16_t Bs[128 * 32];  // 8 KB

    const int tid = threadIdx.x, w = tid >> 6, lane = tid & 63;
    const int quad = lane >> 4, c = lane & 15;
    const int wm = (w >> 1) * 64, wn = (w & 1) * 64;
    const int m0 = blockIdx.y * 128, n0 = blockIdx.x * 128;

    const int z = blockIdx.z;
    const bf16_t* W = (z == 0) ? Wt0 : (z == 1) ? Wt1 : Wt2;
    const float* bias = (z == 0) ? b0 : (z == 1) ? b1 : b2;
    TO* out = (z == 0) ? o0 : (z == 1) ? o1 : o2;
    const int mode = (z == 0) ? md0 : (z == 1) ? md1 : md2;
    const float scale = (z == 0) ? sc0 : (z == 1) ? sc1 : sc2;

    f32x4 acc[4][4];
#pragma unroll
    for (int i = 0; i < 4; ++i)
#pragma unroll
        for (int j = 0; j < 4; ++j) acc[i][j] = (f32x4){0.f, 0.f, 0.f, 0.f};

    const int srow = lane >> 2, schunk = lane & 3;  // 16 rows x 4 chunks / instr
    const bf16_t* Ag = A + (size_t)m0 * 1024;
    const bf16_t* Bg = W + (size_t)n0 * 1024;

    for (int k0 = 0; k0 < 1024; k0 += 32) {
        __syncthreads();  // prior iteration's frag reads complete
#pragma unroll
        for (int s = 0; s < 2; ++s) {
            int rg = (w * 2 + s) * 16;  // wave-uniform row-group base
            gld16(&As[rg * 32], &Ag[(size_t)(rg + srow) * 1024 + k0 + schunk * 8]);
            gld16(&Bs[rg * 32], &Bg[(size_t)(rg + srow) * 1024 + k0 + schunk * 8]);
        }
        __syncthreads();  // drains vmcnt -> tiles in LDS

        bf16x8 af[4], bfv[4];
#pragma unroll
        for (int t = 0; t < 4; ++t)
            af[t] = *(const bf16x8*)&As[(wm + t * 16 + c) * 32 + quad * 8];
#pragma unroll
        for (int t = 0; t < 4; ++t)
            bfv[t] = *(const bf16x8*)&Bs[(wn + t * 16 + c) * 32 + quad * 8];
#pragma unroll
        for (int mt = 0; mt < 4; ++mt)
#pragma unroll
            for (int nt = 0; nt < 4; ++nt)
                acc[mt][nt] = __builtin_amdgcn_mfma_f32_16x16x32_bf16(
                    af[mt], bfv[nt], acc[mt][nt], 0, 0, 0);
    }

    // Epilogue. C/D layout: row = quad*4+r, col = c.
#pragma unroll
    for (int nt = 0; nt < 4; ++nt) {
        int col = n0 + wn + nt * 16 + c;
        float bv = bias[col];
#pragma unroll
        for (int mt = 0; mt < 4; ++mt)
#pragma unroll
            for (int r = 0; r < 4; ++r) {
                int row = m0 + wm + mt * 16 + quad * 4 + r;
                float v = (acc[mt][nt][r] + bv) * scale;
                size_t idx;
                if (mode == 0) {
                    idx = (size_t)row * 1024 + col;
                } else {
                    int bb = row >> 11, n = row & 2047;
                    int hh = col >> 6, d = col & 63;
                    idx = (mode == 1) ? ((size_t)(bb * HEADS + hh) * SEQ + n) * HD + d
                                      : ((size_t)(bb * HEADS + hh) * HD + d) * SEQ + n;
                }
                out[idx] = (TO)v;
            }
    }
}

// ---------------------------------------------------------------------------
// Flash attention, 32x32 MFMA, swapped QK^T, in-register softmax.
//   4 waves x 32 q-rows = 128 q-rows/block, KV tile 64, double-buffered.
// Swapped QK^T: St[kb] = mfma(K-frag, Q-frag) -> col = lane&31 = q (lane-local
// P row), row k' = (reg&3)+8*(reg>>2)+4*(lane>>5). P -> PV A-frag via
// v_cvt_pk_bf16_f32 + v_permlane32_swap_b32 (T12): no P LDS round trip.
// No-max-sub softmax as before (S = qk/32, overflow impossible).
// Staging: issue next tile's global_load_lds at loop top; single barrier/iter
// (compiler's vmcnt drain at the barrier lands after the compute phase).
// ---------------------------------------------------------------------------
__global__ __launch_bounds__(256) void attn_kernel(
    const bf16_t* __restrict__ Q, const bf16_t* __restrict__ K,
    const bf16_t* __restrict__ Vt, bf16_t* __restrict__ O) {
    __shared__ __align__(16) bf16_t Qs[128 * 64];     // 16 KB
    __shared__ __align__(16) bf16_t Ks[2][64 * 64];   // 16 KB
    __shared__ __align__(16) bf16_t Vs[2][64 * 64];   // 16 KB

    const int tid = threadIdx.x, w = tid >> 6, lane = tid & 63;
    const int hi = lane >> 5, lq = lane & 31;
    const int bh = blockIdx.y, b = bh >> 4, h = bh & 15;
    const int q0 = blockIdx.x * 128;

    const int srow8 = lane >> 3, sch = lane & 7;  // 8 rows x 8 chunks / instr

    const bf16_t* Qg = Q + ((size_t)bh * SEQ + q0) * HD;
    const bf16_t* Kg0 = K + (size_t)bh * SEQ * HD;
    const bf16_t* Vg0 = Vt + (size_t)bh * HD * SEQ;

    // prologue: stage Q tile (128x64) + K/V tile 0 into buf 0 (swizzled src)
#pragma unroll
    for (int s = 0; s < 4; ++s) {
        int rg = (w * 4 + s) * 8;
        int row = rg + srow8;
        int g = sch ^ (row & 7);
        gld16(&Qs[rg * 64], &Qg[(size_t)row * 64 + g * 8]);
    }
#pragma unroll
    for (int s = 0; s < 2; ++s) {
        int rg = (w * 2 + s) * 8;
        int row = rg + srow8;
        int g = sch ^ (row & 7);
        gld16(&Ks[0][rg * 64], &Kg0[(size_t)row * 64 + g * 8]);
        gld16(&Vs[0][rg * 64], &Vg0[(size_t)row * SEQ + g * 8]);
    }
    __syncthreads();  // drains vmcnt -> Q + tile0 in LDS

    // hoist Q B-frags (loop-invariant): lane holds Q[w*32+lq][dc*16+hi*8 ..+8]
    bf16x8 qf[4];
    {
        int row = w * 32 + lq;
#pragma unroll
        for (int dc = 0; dc < 4; ++dc)
            qf[dc] = *(const bf16x8*)&Qs[row * 64 + (((dc * 2 + hi) ^ (row & 7)) * 8)];
    }

    f32x16 Oacc0, Oacc1;
#pragma unroll
    for (int r = 0; r < 16; ++r) { Oacc0[r] = 0.f; Oacc1[r] = 0.f; }
    float lp = 0.f;

    for (int t = 0; t < SEQ / 64; ++t) {
        const int cur = t & 1;
        if (t + 1 < SEQ / 64) {  // issue next tile's DMA early (overlaps compute)
            const bf16_t* Kg = Kg0 + (size_t)(t + 1) * 64 * HD;
            const bf16_t* Vg = Vg0 + (t + 1) * 64;
#pragma unroll
            for (int s = 0; s < 2; ++s) {
                int rg = (w * 2 + s) * 8;
                int row = rg + srow8;
                int g = sch ^ (row & 7);
                gld16(&Ks[cur ^ 1][rg * 64], &Kg[(size_t)row * 64 + g * 8]);
                gld16(&Vs[cur ^ 1][rg * 64], &Vg[(size_t)row * SEQ + g * 8]);
            }
        }

        // QK^T (swapped): St[kb][k'][q], contraction over d in 4 chunks of 16
        f32x16 St0, St1;
#pragma unroll
        for (int r = 0; r < 16; ++r) { St0[r] = 0.f; St1[r] = 0.f; }
        __builtin_amdgcn_s_setprio(1);
#pragma unroll
        for (int dc = 0; dc < 4; ++dc) {
            int r0 = lq, r1 = 32 + lq;
            bf16x8 k0 = *(const bf16x8*)&Ks[cur][r0 * 64 + (((dc * 2 + hi) ^ (r0 & 7)) * 8)];
            bf16x8 k1 = *(const bf16x8*)&Ks[cur][r1 * 64 + (((dc * 2 + hi) ^ (r1 & 7)) * 8)];
            St0 = __builtin_amdgcn_mfma_f32_32x32x16_bf16(k0, qf[dc], St0, 0, 0, 0);
            St1 = __builtin_amdgcn_mfma_f32_32x32x16_bf16(k1, qf[dc], St1, 0, 0, 0);
        }
        __builtin_amdgcn_s_setprio(0);

        // P = exp(S) in place; per-lane row-sum partial (lane owns q = lq)
#pragma unroll
        for (int r = 0; r < 16; ++r) {
            St0[r] = __expf(St0[r]); lp += St0[r];
            St1[r] = __expf(St1[r]); lp += St1[r];
        }

        // P -> PV A-frags: frag f covers k = f*16 + hi*8 + j (f = kb*2 + c2).
        // word wj needs reg i+4*(2*c2+hi_dest) from hi_src = wj>>1 partner:
        // a' = w0, c' = w1, b' = w2, d' = w3 after two permlane32_swaps.
        bf16x8 pf[4];
#define PACKFRAG(SS, c2, dstIdx)                                              \
        {                                                                      \
            unsigned pa = cvt_pk_bf16(SS[8 * (c2) + 0], SS[8 * (c2) + 1]);     \
            unsigned pb = cvt_pk_bf16(SS[8 * (c2) + 4], SS[8 * (c2) + 5]);     \
            unsigned pc = cvt_pk_bf16(SS[8 * (c2) + 2], SS[8 * (c2) + 3]);     \
            unsigned pd = cvt_pk_bf16(SS[8 * (c2) + 6], SS[8 * (c2) + 7]);     \
            asm volatile("v_permlane32_swap_b32 %0, %1" : "+v"(pa), "+v"(pb)); \
            asm volatile("v_permlane32_swap_b32 %0, %1" : "+v"(pc), "+v"(pd)); \
            union { unsigned u[4]; bf16x8 v; } pu;                             \
            pu.u[0] = pa; pu.u[1] = pc; pu.u[2] = pb; pu.u[3] = pd;            \
            pf[dstIdx] = pu.v;                                                 \
        }
        PACKFRAG(St0, 0, 0)
        PACKFRAG(St0, 1, 1)
        PACKFRAG(St1, 0, 2)
        PACKFRAG(St1, 1, 3)
#undef PACKFRAG

        // O += P V : A = P-frag, B = Vt[d][k] rows (n = d = lane&31)
        __builtin_amdgcn_s_setprio(1);
#pragma unroll
        for (int f = 0; f < 4; ++f) {
            int d0 = lq, d1 = 32 + lq;
            bf16x8 v0 = *(const bf16x8*)&Vs[cur][d0 * 64 + (((f * 2 + hi) ^ (d0 & 7)) * 8)];
            bf16x8 v1 = *(const bf16x8*)&Vs[cur][d1 * 64 + (((f * 2 + hi) ^ (d1 & 7)) * 8)];
            Oacc0 = __builtin_amdgcn_mfma_f32_32x32x16_bf16(pf[f], v0, Oacc0, 0, 0, 0);
            Oacc1 = __builtin_amdgcn_mfma_f32_32x32x16_bf16(pf[f], v1, Oacc1, 0, 0, 0);
        }
        __builtin_amdgcn_s_setprio(0);

        __syncthreads();  // all frag reads of buf[cur] done; next tile's DMA drained
    }

    // complete row sums: lane and lane^32 hold complementary k'-halves of q=lq
    lp += __shfl_xor(lp, 32);
    float rl = 1.0f / lp;

    // C/D layout: col = d = lane&31, row = q_loc = (r&3)+8*(r>>2)+4*hi
#pragma unroll
    for (int r = 0; r < 16; ++r) {
        int q_loc = (r & 3) + 8 * (r >> 2) + 4 * hi;
        float rr = __shfl(rl, q_loc);  // lanes 0..31 hold full lp for q=lane&31
        int qrow = q0 + w * 32 + q_loc;
        size_t base = ((size_t)(b * SEQ + qrow)) * EMB + h * 64;
        O[base + lq] = (bf16_t)(Oacc0[r] * rr);
        O[base + 32 + lq] = (bf16_t)(Oacc1[r] * rr);
    }
}

// ---------------------------------------------------------------------------
extern "C" void kernel_launch(void* const* d_in, const int* in_sizes, int n_in,
                              void* d_out, int out_size, void* d_ws, size_t ws_size,
                              hipStream_t stream) {
    (void)in_sizes; (void)n_in; (void)out_size; (void)ws_size;
    const float* x  = (const float*)d_in[0];
    const float* Wq = (const float*)d_in[1];
    const float* bq = (const float*)d_in[2];
    const float* Wk = (const float*)d_in[3];
    const float* bk = (const float*)d_in[4];
    const float* Wv = (const float*)d_in[5];
    const float* bv = (const float*)d_in[6];
    const float* Wo = (const float*)d_in[7];
    const float* bo = (const float*)d_in[8];

    bf16_t* ws = (bf16_t*)d_ws;
    const size_t NELEM = (size_t)TOKENS * EMB;  // 4M
    const size_t WELEM = (size_t)EMB * EMB;     // 1M
    bf16_t* Qb  = ws;
    bf16_t* Kb  = ws + NELEM;
    bf16_t* Vb  = ws + 2 * NELEM;
    bf16_t* Ob  = ws + 3 * NELEM;
    bf16_t* xb  = ws + 4 * NELEM;
    bf16_t* Wt0 = ws + 5 * NELEM;
    bf16_t* Wt1 = Wt0 + WELEM;
    bf16_t* Wt2 = Wt0 + 2 * WELEM;
    bf16_t* Wt3 = Wt0 + 3 * WELEM;  // total 48 MB of d_ws

    hipLaunchKernelGGL(convert_x, dim3(1024), dim3(256), 0, stream, x, xb);
    hipLaunchKernelGGL(prep_w, dim3(16, 16, 4), dim3(256), 0, stream,
                       Wq, Wk, Wv, Wo, Wt0, Wt1, Wt2, Wt3);
    // fused QKV: z=0 Q(mode1, scale 1/32), z=1 K(mode1), z=2 V(mode2)
    hipLaunchKernelGGL((gemm128<bf16_t>), dim3(8, 32, 3), dim3(256), 0, stream,
                       xb, Wt0, Wt1, Wt2, bq, bk, bv, Qb, Kb, Vb,
                       1, 1, 2, 0.03125f, 1.0f, 1.0f);
    hipLaunchKernelGGL(attn_kernel, dim3(16, 32), dim3(256), 0, stream, Qb, Kb, Vb, Ob);
    hipLaunchKernelGGL((gemm128<float>), dim3(8, 32, 1), dim3(256), 0, stream,
                       Ob, Wt3, Wt3, Wt3, bo, bo, bo,
                       (float*)d_out, (float*)d_out, (float*)d_out,
                       0, 0, 0, 1.0f, 1.0f, 1.0f);
}